// Round 3
// baseline (197.120 us; speedup 1.0000x reference)
//
#include <hip/hip_runtime.h>
#include <hip/hip_bf16.h>

// SelfAttention B=4 S=2048 D=1024:
//   out = softmax((xWq^T+bq)(xWk^T+bk)^T / 32) (xWv^T+bv)
// 8-phase-style deep-pipelined bf16 MFMA GEMMs (counted vmcnt, raw barriers,
// setprio, XOR LDS swizzle, bijective XCD block swizzle).
// ws: xb[8192*1024]bf16 | wqb,wkb,wvb[1024²]bf16 contig | qb,kb[8192*1024]bf16 |
//     vtb[4][1024][2048]bf16 | sc[nb][2048²]fp32 (softmax writes bf16 P in-place
//     at row stride 4096 bf16)

typedef __hip_bfloat16 bf16;
typedef __attribute__((ext_vector_type(8))) short bf16x8;
typedef __attribute__((ext_vector_type(4))) float f32x4;
typedef __attribute__((ext_vector_type(4))) short short4v;

__device__ __forceinline__ void gload16(const bf16* g, bf16* l) {
  __builtin_amdgcn_global_load_lds(
      (const __attribute__((address_space(1))) void*)g,
      (__attribute__((address_space(3))) void*)l, 16, 0, 0);
}

#define WAITV(N) asm volatile("s_waitcnt vmcnt(" #N ")" ::: "memory")
#define LGKM0   asm volatile("s_waitcnt lgkmcnt(0)" ::: "memory")
#define SCHED0  __builtin_amdgcn_sched_barrier(0)
#define BAR     __builtin_amdgcn_s_barrier()
#define PRIO1   __builtin_amdgcn_s_setprio(1)
#define PRIO0   __builtin_amdgcn_s_setprio(0)

__global__ __launch_bounds__(256)
void cast_f32_to_bf16(const float* __restrict__ in, bf16* __restrict__ out) {
  long i = ((long)blockIdx.x * blockDim.x + threadIdx.x) * 4;
  float4 f = *(const float4*)(in + i);
  bf16 tmp[4];
  tmp[0] = __float2bfloat16(f.x);
  tmp[1] = __float2bfloat16(f.y);
  tmp[2] = __float2bfloat16(f.z);
  tmp[3] = __float2bfloat16(f.w);
  *(short4v*)(out + i) = *(short4v*)tmp;
}

// ---- common helpers -------------------------------------------------------
// XCD-bijective swizzle + block coord decode (x fastest within an XCD chunk)
__device__ __forceinline__ void xcd_coords(int& bx, int& by, int& bz) {
  const int gx = gridDim.x, gy = gridDim.y;
  const int nwg = gx * gy * gridDim.z;
  int n0 = blockIdx.x + gx * (blockIdx.y + gy * blockIdx.z);
  int q = nwg >> 3, r = nwg & 7;
  int xcd = n0 & 7, idx = n0 >> 3;
  int n1 = (xcd < r ? xcd * (q + 1) : r * (q + 1) + (xcd - r) * q) + idx;
  bz = n1 / (gx * gy);
  int rem = n1 % (gx * gy);
  by = rem / gx;
  bx = rem % gx;
}

// =====================  BM=256, BN=256, BK=64, 512 thr  ====================
// 8 waves (2M x 4N), per-wave 128x64, frags 8m x 4n. 4 phases/K-tile,
// 16 MFMA each: (mh0,nh0)(mh0,nh1)(mh1,nh0)(mh1,nh1).
// LDS: A,B 2x32KB each = 128KB. XOR swizzle: 16B chunk j of row r stored at
// j^(r&7) (storage linear; source pre-swizzled; proven 0-conflict).
__global__ __launch_bounds__(512)
void gemm8p_n256(const bf16* __restrict__ A, const bf16* __restrict__ Bt,
                 float* __restrict__ C, int K, int lda, int ldb, int ldc,
                 float scale, long sA, long sB, long sC)
{
  __shared__ __align__(16) bf16 As[2][256 * 64];
  __shared__ __align__(16) bf16 Bs[2][256 * 64];
  const int tid = threadIdx.x;
  const int wid = tid >> 6, lane = tid & 63, l15 = lane & 15, kg = lane >> 4;
  const int wr = wid >> 2, wc = wid & 3;
  int bxi, byi, bz;
  xcd_coords(bxi, byi, bz);
  const long bm = (long)bxi * 256, bn = (long)byi * 256;
  const bf16* Ab = A + (long)bz * sA;
  const bf16* Bb = Bt + (long)bz * sB;

  // staging slots (storage-linear enumeration; src col pre-swizzled)
  const bf16 *srcA0[2], *srcA1[2], *srcB0[2], *srcB1[2];
  int ldsA0[2], ldsA1[2], ldsB0[2], ldsB1[2];
#pragma unroll
  for (int l = 0; l < 2; ++l) {
    const int s = l * 512 + tid;
    const int r0 = s >> 3;
    {  // A0: rows {0-63, 128-191}
      int row = (r0 < 64) ? r0 : r0 + 64;
      int j = (s & 7) ^ (row & 7);
      srcA0[l] = Ab + (bm + row) * lda + (j << 3);
      ldsA0[l] = (l ? 1024 : 0) + (wid << 6);
    }
    {  // A1: rows {64-127, 192-255}
      int row = (r0 < 64) ? r0 + 64 : r0 + 128;
      int j = (s & 7) ^ (row & 7);
      srcA1[l] = Ab + (bm + row) * lda + (j << 3);
      ldsA1[l] = (l ? 1536 : 512) + (wid << 6);
    }
    {  // B0: rows == [0,31] mod 64
      int row = ((r0 >> 5) << 6) + (r0 & 31);
      int j = (s & 7) ^ (row & 7);
      srcB0[l] = Bb + (bn + row) * ldb + (j << 3);
      int r0b = (l << 6) + (wid << 3);
      ldsB0[l] = ((((r0b >> 5) << 6) + (r0b & 31)) << 3);
    }
    {  // B1: rows == [32,63] mod 64
      int row = ((r0 >> 5) << 6) + 32 + (r0 & 31);
      int j = (s & 7) ^ (row & 7);
      srcB1[l] = Bb + (bn + row) * ldb + (j << 3);
      int r0b = (l << 6) + (wid << 3);
      ldsB1[l] = ((((r0b >> 5) << 6) + 32 + (r0b & 31)) << 3);
    }
  }

#define STG(SRC, LDS, NX, K0)                                         \
  do { _Pragma("unroll") for (int l = 0; l < 2; ++l)                  \
    gload16(SRC[l] + (K0), &((NX)[(LDS[l]) << 3])); } while (0)

  bf16x8 af[2][4], b0f[2][2], b1f[2][2];
  f32x4 acc[8][4];
#pragma unroll
  for (int m = 0; m < 8; ++m)
#pragma unroll
    for (int n = 0; n < 4; ++n) acc[m][n] = (f32x4){0.f, 0.f, 0.f, 0.f};

#define READ_A(CUR, MH)                                               \
  do { _Pragma("unroll") for (int kk = 0; kk < 2; ++kk)               \
    _Pragma("unroll") for (int mi = 0; mi < 4; ++mi) {                \
      int row_l = wr * 128 + ((MH) * 4 + mi) * 16 + l15;              \
      int js = ((kk << 2) + kg) ^ (row_l & 7);                        \
      af[kk][mi] = *(const bf16x8*)&(CUR)[(row_l << 6) + (js << 3)];  \
    } } while (0)
#define READ_B(CUR, NH, DST)                                          \
  do { _Pragma("unroll") for (int kk = 0; kk < 2; ++kk)               \
    _Pragma("unroll") for (int ni = 0; ni < 2; ++ni) {                \
      int row_l = wc * 64 + ((NH) * 2 + ni) * 16 + l15;               \
      int js = ((kk << 2) + kg) ^ (row_l & 7);                        \
      DST[kk][ni] = *(const bf16x8*)&(CUR)[(row_l << 6) + (js << 3)]; \
    } } while (0)
#define MFMA16(MH, NH, BF)                                            \
  do { _Pragma("unroll") for (int kk = 0; kk < 2; ++kk)               \
    _Pragma("unroll") for (int mi = 0; mi < 4; ++mi)                  \
    _Pragma("unroll") for (int ni = 0; ni < 2; ++ni)                  \
      acc[(MH)*4+mi][(NH)*2+ni] = __builtin_amdgcn_mfma_f32_16x16x32_bf16( \
          af[kk][mi], BF[kk][ni], acc[(MH)*4+mi][(NH)*2+ni], 0, 0, 0);\
  } while (0)

  const int T = K >> 6;
  // prologue: tile0 in issue order A0,B0 | B1 | A1
  STG(srcA0, ldsA0, As[0], 0);
  STG(srcB0, ldsB0, Bs[0], 0);
  STG(srcB1, ldsB1, Bs[0], 0);
  STG(srcA1, ldsA1, As[0], 0);
  WAITV(4);
  BAR;

  for (int t = 0; t < T; ++t) {
    bf16* Ac = As[t & 1];
    bf16* Bc = Bs[t & 1];
    bf16* An = As[(t & 1) ^ 1];
    bf16* Bn = Bs[(t & 1) ^ 1];
    const int kn = (t + 1) << 6;
    const bool pre = (t + 1) < T;
    // ---- Q1: (mh0, nh0) ----
    READ_A(Ac, 0);
    READ_B(Bc, 0, b0f);
    if (pre) { STG(srcA0, ldsA0, An, kn); STG(srcB0, ldsB0, Bn, kn); }
    if (pre) WAITV(6); else WAITV(2);
    BAR; LGKM0; SCHED0; PRIO1;
    MFMA16(0, 0, b0f);
    PRIO0; SCHED0; BAR;
    // ---- Q2: (mh0, nh1) ----
    READ_B(Bc, 1, b1f);
    if (pre) STG(srcB1, ldsB1, Bn, kn);
    if (pre) WAITV(6); else WAITV(0);
    BAR; LGKM0; SCHED0; PRIO1;
    MFMA16(0, 1, b1f);
    PRIO0; SCHED0; BAR;
    // ---- Q3: (mh1, nh0) ----
    READ_A(Ac, 1);
    if (pre) STG(srcA1, ldsA1, An, kn);
    BAR; LGKM0; SCHED0; PRIO1;
    MFMA16(1, 0, b0f);
    PRIO0; SCHED0; BAR;
    // ---- Q4: (mh1, nh1) ----
    if (pre) WAITV(4);
    BAR; PRIO1;
    MFMA16(1, 1, b1f);
    PRIO0; SCHED0; BAR;
  }

  float* Cz = C + (long)bz * sC;
#pragma unroll
  for (int m = 0; m < 8; ++m) {
    const long row0 = bm + wr * 128 + m * 16 + (kg << 2);
#pragma unroll
    for (int n = 0; n < 4; ++n) {
      const long col = bn + wc * 64 + n * 16 + l15;
#pragma unroll
      for (int rr = 0; rr < 4; ++rr)
        Cz[(row0 + rr) * ldc + col] = acc[m][n][rr] * scale;
    }
  }
#undef READ_A
#undef READ_B
#undef MFMA16
#undef STG
}

// =====================  BM=256, BN=128, BK=64, 512 thr  ====================
// 8 waves (2M x 4N), per-wave 128x32, frags 8m x 2n. 2 phases/K-tile (mh0,mh1),
// 16 MFMA each. LDS: A 2x32KB + B 2x16KB = 96KB.
// OMODE 0: fp32 C=scale*(A Bt^T) at Cout+bz*sC.  OMODE 3: QKV combo (bz=z).
template<int OMODE>
__global__ __launch_bounds__(512)
void gemm8p_n128(const bf16* __restrict__ A, const bf16* __restrict__ Bt,
                 const float* __restrict__ b0, const float* __restrict__ b1,
                 const float* __restrict__ b2, void* __restrict__ Cout,
                 int K, int lda, int ldb, int ldc, float scale,
                 long sA, long sB, long sC)
{
  __shared__ __align__(16) bf16 As[2][256 * 64];
  __shared__ __align__(16) bf16 Bs[2][128 * 64];
  const int tid = threadIdx.x;
  const int wid = tid >> 6, lane = tid & 63, l15 = lane & 15, kg = lane >> 4;
  const int wr = wid >> 2, wc = wid & 3;
  int bxi, byi, bz;
  xcd_coords(bxi, byi, bz);
  const long bm = (long)bxi * 256, bn = (long)byi * 128;
  const bf16* Ab = A + (long)bz * sA;
  const bf16* Bb = Bt + (long)bz * sB;

  const bf16 *srcA0[2], *srcA1[2], *srcBw[2];
  int ldsA0[2], ldsA1[2], ldsBw[2];
#pragma unroll
  for (int l = 0; l < 2; ++l) {
    const int s = l * 512 + tid;
    const int r0 = s >> 3;
    {
      int row = (r0 < 64) ? r0 : r0 + 64;            // A0
      int j = (s & 7) ^ (row & 7);
      srcA0[l] = Ab + (bm + row) * lda + (j << 3);
      ldsA0[l] = (l ? 1024 : 0) + (wid << 6);
    }
    {
      int row = (r0 < 64) ? r0 + 64 : r0 + 128;      // A1
      int j = (s & 7) ^ (row & 7);
      srcA1[l] = Ab + (bm + row) * lda + (j << 3);
      ldsA1[l] = (l ? 1536 : 512) + (wid << 6);
    }
    {
      int row = r0;                                   // B whole (128 rows)
      int j = (s & 7) ^ (row & 7);
      srcBw[l] = Bb + (bn + row) * ldb + (j << 3);
      ldsBw[l] = l * 512 + (wid << 6);
    }
  }

#define STG(SRC, LDS, NX, K0)                                         \
  do { _Pragma("unroll") for (int l = 0; l < 2; ++l)                  \
    gload16(SRC[l] + (K0), &((NX)[(LDS[l]) << 3])); } while (0)

  bf16x8 af[2][4], bf_[2][2];
  f32x4 acc[8][2];
#pragma unroll
  for (int m = 0; m < 8; ++m)
#pragma unroll
    for (int n = 0; n < 2; ++n) acc[m][n] = (f32x4){0.f, 0.f, 0.f, 0.f};

#define READ_A(CUR, MH)                                               \
  do { _Pragma("unroll") for (int kk = 0; kk < 2; ++kk)               \
    _Pragma("unroll") for (int mi = 0; mi < 4; ++mi) {                \
      int row_l = wr * 128 + ((MH) * 4 + mi) * 16 + l15;              \
      int js = ((kk << 2) + kg) ^ (row_l & 7);                        \
      af[kk][mi] = *(const bf16x8*)&(CUR)[(row_l << 6) + (js << 3)];  \
    } } while (0)
#define READ_B(CUR)                                                   \
  do { _Pragma("unroll") for (int kk = 0; kk < 2; ++kk)               \
    _Pragma("unroll") for (int ni = 0; ni < 2; ++ni) {                \
      int row_l = wc * 32 + ni * 16 + l15;                            \
      int js = ((kk << 2) + kg) ^ (row_l & 7);                        \
      bf_[kk][ni] = *(const bf16x8*)&(CUR)[(row_l << 6) + (js << 3)]; \
    } } while (0)
#define MFMA16(MH)                                                    \
  do { _Pragma("unroll") for (int kk = 0; kk < 2; ++kk)               \
    _Pragma("unroll") for (int mi = 0; mi < 4; ++mi)                  \
    _Pragma("unroll") for (int ni = 0; ni < 2; ++ni)                  \
      acc[(MH)*4+mi][ni] = __builtin_amdgcn_mfma_f32_16x16x32_bf16(   \
          af[kk][mi], bf_[kk][ni], acc[(MH)*4+mi][ni], 0, 0, 0);      \
  } while (0)

  const int T = K >> 6;
  STG(srcA0, ldsA0, As[0], 0);
  STG(srcBw, ldsBw, Bs[0], 0);
  STG(srcA1, ldsA1, As[0], 0);
  WAITV(2);
  BAR;

  for (int t = 0; t < T; ++t) {
    bf16* Ac = As[t & 1];
    bf16* Bc = Bs[t & 1];
    bf16* An = As[(t & 1) ^ 1];
    bf16* Bn = Bs[(t & 1) ^ 1];
    const int kn = (t + 1) << 6;
    const bool pre = (t + 1) < T;
    // ---- P1 (mh0) ----
    READ_A(Ac, 0);
    READ_B(Bc);
    if (pre) { STG(srcA0, ldsA0, An, kn); STG(srcBw, ldsBw, Bn, kn); }
    if (pre) WAITV(4); else WAITV(0);
    BAR; LGKM0; SCHED0; PRIO1;
    MFMA16(0);
    PRIO0; SCHED0; BAR;
    // ---- P2 (mh1) ----
    READ_A(Ac, 1);
    if (pre) STG(srcA1, ldsA1, An, kn);
    if (pre) WAITV(2);
    BAR; LGKM0; SCHED0; PRIO1;
    MFMA16(1);
    PRIO0; SCHED0; BAR;
  }

#pragma unroll
  for (int m = 0; m < 8; ++m) {
    const long row0 = bm + wr * 128 + m * 16 + (kg << 2);
#pragma unroll
    for (int n = 0; n < 2; ++n) {
      const long col = bn + wc * 32 + n * 16 + l15;
      if constexpr (OMODE == 0) {
        float* C = (float*)Cout + (long)bz * sC;
#pragma unroll
        for (int rr = 0; rr < 4; ++rr)
          C[(row0 + rr) * ldc + col] = acc[m][n][rr] * scale;
      } else {  // QKV combo
        const float* bias = (bz == 0) ? b0 : (bz == 1) ? b1 : b2;
        const float bias_v = bias[col];
        if (bz < 2) {
          bf16* C = (bf16*)Cout + (long)bz * 8192 * 1024;
#pragma unroll
          for (int rr = 0; rr < 4; ++rr)
            C[(row0 + rr) * 1024 + col] = __float2bfloat16(acc[m][n][rr] + bias_v);
        } else {
          bf16* C = (bf16*)Cout + 2L * 8192 * 1024;  // vtb
          const long bb = row0 >> 11;
          const long s0 = row0 & 2047;
          bf16 tmp[4];
#pragma unroll
          for (int rr = 0; rr < 4; ++rr)
            tmp[rr] = __float2bfloat16(acc[m][n][rr] + bias_v);
          *(short4v*)&C[(bb * 1024 + col) * 2048 + s0] = *(short4v*)tmp;
        }
      }
    }
  }
#undef READ_A
#undef READ_B
#undef MFMA16
#undef STG
}

// softmax: one block per 2048-col fp32 row; bf16 P written in-place.
__global__ __launch_bounds__(256)
void softmax_inplace_bf16(float* __restrict__ S) {
  float* row = S + (size_t)blockIdx.x * 2048;
  const int tid = threadIdx.x;
  __shared__ float redA[4], redB[4];
  float v[8];
  float mx = -1e30f;
#pragma unroll
  for (int i = 0; i < 8; ++i) {
    v[i] = row[tid + (i << 8)];
    mx = fmaxf(mx, v[i]);
  }
#pragma unroll
  for (int o = 32; o; o >>= 1) mx = fmaxf(mx, __shfl_xor(mx, o));
  if ((tid & 63) == 0) redA[tid >> 6] = mx;
  __syncthreads();
  mx = fmaxf(fmaxf(redA[0], redA[1]), fmaxf(redA[2], redA[3]));
  float sum = 0.f;
#pragma unroll
  for (int i = 0; i < 8; ++i) {
    v[i] = __expf(v[i] - mx);
    sum += v[i];
  }
#pragma unroll
  for (int o = 32; o; o >>= 1) sum += __shfl_xor(sum, o);
  if ((tid & 63) == 0) redB[tid >> 6] = sum;
  __syncthreads();
  sum = redB[0] + redB[1] + redB[2] + redB[3];
  const float inv = 1.f / sum;
  bf16* po = (bf16*)row;
#pragma unroll
  for (int i = 0; i < 8; ++i)
    po[tid + (i << 8)] = __float2bfloat16(v[i] * inv);
}

extern "C" void kernel_launch(void* const* d_in, const int* in_sizes, int n_in,
                              void* d_out, int out_size, void* d_ws, size_t ws_size,
                              hipStream_t stream) {
  const float* x  = (const float*)d_in[0];
  const float* Wq = (const float*)d_in[1];
  const float* bq = (const float*)d_in[2];
  const float* Wk = (const float*)d_in[3];
  const float* bk = (const float*)d_in[4];
  const float* Wv = (const float*)d_in[5];
  const float* bv = (const float*)d_in[6];
  float* out = (float*)d_out;

  const int B = 4, S = 2048, D = 1024;
  const int M = B * S;  // 8192

  bf16* xb  = (bf16*)d_ws;
  bf16* wqb = xb + (size_t)M * D;       // wqb,wkb,wvb contiguous
  bf16* qb  = wqb + 3 * (size_t)D * D;
  bf16* kb  = qb + (size_t)M * D;
  bf16* vtb = kb + (size_t)M * D;
  float* sc = (float*)(vtb + (size_t)M * D);

  size_t avail = ws_size - ((size_t)((char*)sc - (char*)d_ws));
  int nb = (int)(avail / ((size_t)S * S * 4));
  if (nb > B) nb = B;
  if (nb < 1) nb = 1;

  // casts
  cast_f32_to_bf16<<<dim3(M * D / 1024), 256, 0, stream>>>(x, xb);
  cast_f32_to_bf16<<<dim3(D * D / 1024), 256, 0, stream>>>(Wq, wqb);
  cast_f32_to_bf16<<<dim3(D * D / 1024), 256, 0, stream>>>(Wk, wqb + (size_t)D * D);
  cast_f32_to_bf16<<<dim3(D * D / 1024), 256, 0, stream>>>(Wv, wqb + 2 * (size_t)D * D);

  // fused QKV projection: BM=256 BN=128, grid 32x8x3 = 768 blocks
  gemm8p_n128<3><<<dim3(M / 256, D / 128, 3), 512, 0, stream>>>(
      xb, wqb, bq, bk, bv, qb, D, D, D, D, 1.f, 0, (long)D * D, 0);

  const float iscale = 1.0f / 32.0f;  // 1/sqrt(1024)
  for (int g = 0; g < B; g += nb) {
    const int gn = (g + nb <= B) ? nb : (B - g);
    // QK^T: BM=BN=256, grid 8x8xgn
    gemm8p_n256<<<dim3(S / 256, S / 256, gn), 512, 0, stream>>>(
        qb + (size_t)g * S * D, kb + (size_t)g * S * D, sc,
        D, D, D, S, iscale, (long)S * D, (long)S * D, (long)S * S);
    softmax_inplace_bf16<<<dim3(gn * S), 256, 0, stream>>>(sc);
    // PV: BM=256 BN=128, K=2048, grid 8x8xgn (P bf16 stride 4096 in sc)
    gemm8p_n128<0><<<dim3(S / 256, D / 128, gn), 512, 0, stream>>>(
        (const bf16*)sc, vtb + (size_t)g * D * S, nullptr, nullptr, nullptr,
        out + (size_t)g * S * D, S, 2 * S, S, D, 1.f,
        2L * S * S, (long)D * S, (long)S * D);
  }
}